// Round 1
// baseline (473.505 us; speedup 1.0000x reference)
//
#include <hip/hip_runtime.h>
#include <hip/hip_bf16.h>

#define NN 8192
#define FIN 512
#define FOUT 256

typedef __attribute__((ext_vector_type(8))) short short8;
typedef __attribute__((ext_vector_type(4))) short short4v;
typedef __attribute__((ext_vector_type(4))) float float4v;

__device__ __forceinline__ short f2bf(float f) {
    union { float f; unsigned u; } v; v.f = f;
    unsigned r = (v.u + 0x7FFFu + ((v.u >> 16) & 1u)) >> 16;
    return (short)r;
}
__device__ __forceinline__ float bf2f(short b) {
    union { unsigned u; float f; } v; v.u = ((unsigned)(unsigned short)b) << 16;
    return v.f;
}

// Kernel 0: Wt[n][k] = bf16(W[k][n])   (256 x 512)
__global__ __launch_bounds__(256) void wt_kernel(const float* __restrict__ W,
                                                 short* __restrict__ Wt) {
    int idx = blockIdx.x * 256 + threadIdx.x;   // 0 .. 131071
    int n = idx >> 9, k = idx & 511;
    Wt[idx] = f2bf(W[k * FOUT + n]);
}

// Kernel 1: h_t[n][m] = bf16( (x @ W)[m][n] ) via 16x16x32 bf16 MFMA.
// One wave computes a 16m x 64n tile. 2048 waves = 512 blocks x 4 waves.
__global__ __launch_bounds__(256) void h_kernel(const float* __restrict__ x,
                                                const short* __restrict__ Wt,
                                                short* __restrict__ h_t) {
    int wave = (blockIdx.x << 2) + (threadIdx.x >> 6);
    int lane = threadIdx.x & 63;
    int m0 = (wave & 511) << 4;    // 512 m-tiles of 16
    int n0 = (wave >> 9) << 6;     // 4 n-tiles of 64
    int lr = lane & 15, lq = lane >> 4;

    const float* xrow = x + (size_t)(m0 + lr) * FIN + lq * 8;
    const short* wbase = Wt + (size_t)(n0 + lr) * FIN + lq * 8;

    float4v acc[4] = {};
    for (int k0 = 0; k0 < FIN; k0 += 32) {
        float4v xa = *(const float4v*)(xrow + k0);
        float4v xb = *(const float4v*)(xrow + k0 + 4);
        short8 a;
        a[0] = f2bf(xa[0]); a[1] = f2bf(xa[1]); a[2] = f2bf(xa[2]); a[3] = f2bf(xa[3]);
        a[4] = f2bf(xb[0]); a[5] = f2bf(xb[1]); a[6] = f2bf(xb[2]); a[7] = f2bf(xb[3]);
#pragma unroll
        for (int ct = 0; ct < 4; ct++) {
            short8 b = *(const short8*)(wbase + (size_t)ct * 16 * FIN + k0);
            acc[ct] = __builtin_amdgcn_mfma_f32_16x16x32_bf16(a, b, acc[ct], 0, 0, 0);
        }
    }
    // D layout: col = lane&15 (n), row = (lane>>4)*4 + reg (m). Write transposed.
#pragma unroll
    for (int ct = 0; ct < 4; ct++) {
#pragma unroll
        for (int reg = 0; reg < 4; reg++) {
            int m = m0 + lq * 4 + reg;
            int n = n0 + ct * 16 + lr;
            h_t[(size_t)n * NN + m] = f2bf(acc[ct][reg]);
        }
    }
}

// Kernel 2: f_src[i] = log2e * sum_n h[i][n]*a[n]; f_dst with a[FOUT+n].
__global__ __launch_bounds__(256) void f_kernel(const short* __restrict__ h_t,
                                                const float* __restrict__ a,
                                                float* __restrict__ f_src,
                                                float* __restrict__ f_dst) {
    int i = blockIdx.x * 256 + threadIdx.x;
    float s = 0.f, d = 0.f;
#pragma unroll 4
    for (int n = 0; n < FOUT; n++) {
        float hv = bf2f(h_t[(size_t)n * NN + i]);
        s = fmaf(hv, a[n], s);
        d = fmaf(hv, a[FOUT + n], d);
    }
    const float LOG2E = 1.4426950408889634f;
    f_src[i] = s * LOG2E;
    f_dst[i] = d * LOG2E;
}

// Kernel 3: fused masked-softmax @ h.  256 blocks x 512 threads (8 waves).
// Block b: rows [b*32, b*32+32), all 256 output features.
// K-loop over j (8192) in steps of 64: P[32][64] computed from adj/f, H^T tile
// [256][64] staged to LDS, O += P @ H via MFMA; l += rowsum(P). out = O/l.
__global__ __launch_bounds__(512) void gat_kernel(const int* __restrict__ adj,
                                                  const short* __restrict__ h_t,
                                                  const float* __restrict__ f_src,
                                                  const float* __restrict__ f_dst,
                                                  float* __restrict__ out) {
    __shared__ short Pt[32 * 72];    // P tile, padded stride 72 (2-way bank alias only)
    __shared__ short Ht[256 * 72];   // H^T tile [n][j], padded stride 72
    __shared__ float l_sm[32];

    const int t = threadIdx.x;
    const int i0 = blockIdx.x * 32;
    const int r = t >> 4;        // 0..31: row within block (P-compute role)
    const int c = t & 15;        // 0..15: 4-col group within 64-wide tile
    const int lane = t & 63;
    const int w = t >> 6;        // wave 0..7
    const int lr = lane & 15, lq = lane >> 4;
    const int n0 = w * 32;       // this wave's output-feature range

    const float fs = f_src[i0 + r];
    const int* adjRow = adj + (size_t)(i0 + r) * NN + c * 4;

    float lpart = 0.f;
    float4v acc[2][2] = {};

    // prefetch first adj / f_dst chunk
    int4 av = *(const int4*)(adjRow);
    float4 fd = *(const float4*)(f_dst + c * 4);

    for (int j0 = 0; j0 < NN; j0 += 64) {
        // ---- compute P tile (fp32 exp, then bf16) ----
        float p[4];
        const float* fdp = (const float*)&fd;
        const int* avp = (const int*)&av;
#pragma unroll
        for (int q = 0; q < 4; q++) {
            float y = fs + fdp[q];
            y = fmaxf(y, 0.2f * y);          // leaky_relu in log2-scaled domain
            float e = exp2f(y);
            p[q] = (avp[q] != 0) ? e : 0.f;
            lpart += p[q];
        }
        short4v pb;
        pb[0] = f2bf(p[0]); pb[1] = f2bf(p[1]); pb[2] = f2bf(p[2]); pb[3] = f2bf(p[3]);
        *(short4v*)&Pt[r * 72 + c * 4] = pb;

        // ---- stage H^T tile: Ht[n][0..63] = h_t[n][j0..j0+63] ----
#pragma unroll
        for (int q = 0; q < 4; q++) {
            int c2 = t + q * 512;            // chunk 0..2047
            int n = c2 >> 3, ko = (c2 & 7) * 8;
            *(int4*)&Ht[n * 72 + ko] = *(const int4*)(h_t + (size_t)n * NN + j0 + ko);
        }

        // ---- prefetch next adj / f_dst before the barrier ----
        if (j0 + 64 < NN) {
            av = *(const int4*)(adjRow + j0 + 64);
            fd = *(const float4*)(f_dst + j0 + 64 + c * 4);
        }
        __syncthreads();

        // ---- MFMA: 2 row-tiles x 2 col-tiles x 2 k-steps ----
#pragma unroll
        for (int kk = 0; kk < 2; kk++) {
            short8 a0 = *(const short8*)&Pt[lr * 72 + kk * 32 + lq * 8];
            short8 a1 = *(const short8*)&Pt[(16 + lr) * 72 + kk * 32 + lq * 8];
            short8 b0 = *(const short8*)&Ht[(n0 + lr) * 72 + kk * 32 + lq * 8];
            short8 b1 = *(const short8*)&Ht[(n0 + 16 + lr) * 72 + kk * 32 + lq * 8];
            acc[0][0] = __builtin_amdgcn_mfma_f32_16x16x32_bf16(a0, b0, acc[0][0], 0, 0, 0);
            acc[0][1] = __builtin_amdgcn_mfma_f32_16x16x32_bf16(a0, b1, acc[0][1], 0, 0, 0);
            acc[1][0] = __builtin_amdgcn_mfma_f32_16x16x32_bf16(a1, b0, acc[1][0], 0, 0, 0);
            acc[1][1] = __builtin_amdgcn_mfma_f32_16x16x32_bf16(a1, b1, acc[1][1], 0, 0, 0);
        }
        __syncthreads();
    }

    // ---- reduce l over the 16 lanes sharing a row (xor masks stay in-group) ----
#pragma unroll
    for (int off = 8; off >= 1; off >>= 1) lpart += __shfl_xor(lpart, off);
    if (c == 0) l_sm[r] = lpart;
    __syncthreads();

    // ---- epilogue: out[i][n] = O[i][n] / l[i] ----
#pragma unroll
    for (int rt = 0; rt < 2; rt++) {
#pragma unroll
        for (int ct = 0; ct < 2; ct++) {
#pragma unroll
            for (int reg = 0; reg < 4; reg++) {
                int m = rt * 16 + lq * 4 + reg;
                int n = n0 + ct * 16 + lr;
                out[(size_t)(i0 + m) * FOUT + n] = acc[rt][ct][reg] / l_sm[m];
            }
        }
    }
}

extern "C" void kernel_launch(void* const* d_in, const int* in_sizes, int n_in,
                              void* d_out, int out_size, void* d_ws, size_t ws_size,
                              hipStream_t stream) {
    const float* x   = (const float*)d_in[0];
    const int*   adj = (const int*)d_in[1];
    const float* W   = (const float*)d_in[2];
    const float* a   = (const float*)d_in[3];
    float* out = (float*)d_out;

    char* ws = (char*)d_ws;
    short* h_t   = (short*)ws;                                  // 4 MB  (256 x 8192 bf16)
    short* Wt    = (short*)(ws + (4u << 20));                   // 256 KB (256 x 512 bf16)
    float* f_src = (float*)(ws + (4u << 20) + (256u << 10));    // 32 KB
    float* f_dst = (float*)(ws + (4u << 20) + (288u << 10));    // 32 KB

    wt_kernel<<<512, 256, 0, stream>>>(W, Wt);
    h_kernel<<<512, 256, 0, stream>>>(x, Wt, h_t);
    f_kernel<<<NN / 256, 256, 0, stream>>>(h_t, a, f_src, f_dst);
    gat_kernel<<<NN / 32, 512, 0, stream>>>(adj, h_t, f_src, f_dst, out);
}

// Round 2
// 448.137 us; speedup vs baseline: 1.0566x; 1.0566x over previous
//
#include <hip/hip_runtime.h>
#include <hip/hip_bf16.h>

#define NN 8192
#define FIN 512
#define FOUT 256
#define JTILE 64

typedef __attribute__((ext_vector_type(8))) short short8;
typedef __attribute__((ext_vector_type(4))) short short4v;
typedef __attribute__((ext_vector_type(4))) float float4v;
typedef __attribute__((ext_vector_type(16))) float float16v;

__device__ __forceinline__ short f2bf(float f) {
    union { float f; unsigned u; } v; v.f = f;
    unsigned r = (v.u + 0x7FFFu + ((v.u >> 16) & 1u)) >> 16;
    return (short)r;
}

// ---------------- Kernel 0: Wt[n][k] = bf16(W[k][n]), tiled transpose ----------------
__global__ __launch_bounds__(256) void wt_kernel(const float* __restrict__ W,
                                                 short* __restrict__ Wt) {
    __shared__ short tile[32][33];
    int tx = threadIdx.x & 31, ty = threadIdx.x >> 5;   // 32 x 8
    int k0 = blockIdx.x * 32, n0 = blockIdx.y * 32;
#pragma unroll
    for (int r = 0; r < 32; r += 8)
        tile[ty + r][tx] = f2bf(W[(size_t)(k0 + ty + r) * FOUT + n0 + tx]);
    __syncthreads();
#pragma unroll
    for (int r = 0; r < 32; r += 8)
        Wt[(size_t)(n0 + ty + r) * FIN + k0 + tx] = tile[tx][ty + r];
}

// ---------------- Kernel 1: h_t[n][m] = bf16((x@W)[m][n]); fused f_src/f_dst ----------------
// wave = 16m x 64n tile, 512 blocks x 4 waves. Also atomically accumulates
// f_src[i] = LOG2E * h[i,:]@a_l, f_dst[i] = LOG2E * h[i,:]@a_r (from fp32 acc).
__global__ __launch_bounds__(256) void h_kernel(const float* __restrict__ x,
                                                const short* __restrict__ Wt,
                                                const float* __restrict__ a,
                                                short* __restrict__ h_t,
                                                float* __restrict__ f_src,
                                                float* __restrict__ f_dst) {
    int wave = (blockIdx.x << 2) + (threadIdx.x >> 6);
    int lane = threadIdx.x & 63;
    int m0 = (wave & 511) << 4;
    int n0 = (wave >> 9) << 6;
    int lr = lane & 15, lq = lane >> 4;

    const float* xrow = x + (size_t)(m0 + lr) * FIN + lq * 8;
    const short* wbase = Wt + (size_t)(n0 + lr) * FIN + lq * 8;

    float4v acc[4] = {};
    for (int k0 = 0; k0 < FIN; k0 += 32) {
        float4v xa = *(const float4v*)(xrow + k0);
        float4v xb = *(const float4v*)(xrow + k0 + 4);
        short8 av;
        av[0] = f2bf(xa[0]); av[1] = f2bf(xa[1]); av[2] = f2bf(xa[2]); av[3] = f2bf(xa[3]);
        av[4] = f2bf(xb[0]); av[5] = f2bf(xb[1]); av[6] = f2bf(xb[2]); av[7] = f2bf(xb[3]);
#pragma unroll
        for (int ct = 0; ct < 4; ct++) {
            short8 bv = *(const short8*)(wbase + (size_t)ct * 16 * FIN + k0);
            acc[ct] = __builtin_amdgcn_mfma_f32_16x16x32_bf16(av, bv, acc[ct], 0, 0, 0);
        }
    }
    // C/D: col = lr (n), row = lq*4 + reg (m).
    float s_part[4] = {0.f, 0.f, 0.f, 0.f};
    float d_part[4] = {0.f, 0.f, 0.f, 0.f};
#pragma unroll
    for (int ct = 0; ct < 4; ct++) {
        int n = n0 + ct * 16 + lr;
        float al = a[n], ar = a[FOUT + n];
#pragma unroll
        for (int reg = 0; reg < 4; reg++) {
            float hv = acc[ct][reg];
            s_part[reg] = fmaf(hv, al, s_part[reg]);
            d_part[reg] = fmaf(hv, ar, d_part[reg]);
            h_t[(size_t)n * NN + (m0 + lq * 4 + reg)] = f2bf(hv);
        }
    }
#pragma unroll
    for (int off = 1; off < 16; off <<= 1) {
#pragma unroll
        for (int reg = 0; reg < 4; reg++) {
            s_part[reg] += __shfl_xor(s_part[reg], off);
            d_part[reg] += __shfl_xor(d_part[reg], off);
        }
    }
    const float LOG2E = 1.4426950408889634f;
    if (lr == 0) {
#pragma unroll
        for (int reg = 0; reg < 4; reg++) {
            atomicAdd(&f_src[m0 + lq * 4 + reg], s_part[reg] * LOG2E);
            atomicAdd(&f_dst[m0 + lq * 4 + reg], d_part[reg] * LOG2E);
        }
    }
}

// ---------------- Kernel 2: fused masked-softmax-numerator @ h (j-sliced) ----------------
// grid (128 rowgroups, SLICES). block 256 thr = 4 waves. Block tile: 64 rows x 256 feats,
// j-slice of len jlen. Wave = 64 rows x 64 feats as 2x2 of 32x32x16 MFMA tiles.
// Writes partial O (fp32) and partial row-sums l to ws; combine kernel finishes.
__global__ __launch_bounds__(256, 2) void gat_kernel(const int* __restrict__ adj,
                                                     const short* __restrict__ h_t,
                                                     const float* __restrict__ f_src,
                                                     const float* __restrict__ f_dst,
                                                     float* __restrict__ Opart,
                                                     float* __restrict__ lpart,
                                                     int jlen) {
    __shared__ short Ht[256 * 72];       // H^T tile [feat][j], stride 72 (16B-aligned rows)
    __shared__ short Pt[64 * 72];        // P tile [row][j]
    __shared__ float Fd[2][64];          // f_dst tile, double-buffered

    const int t = threadIdx.x;
    const int i0 = blockIdx.x * 64;
    const int slice = blockIdx.y;
    const int jbase = slice * jlen;

    const int prow = t >> 2, pjq = t & 3;           // P-compute role: 64 rows x 4 j-quads
    const int lane = t & 63, w = t >> 6;
    const int l31 = lane & 31, lq = lane >> 5;
    const int wn0 = w * 64;                          // wave's feature base

    const float fs = f_src[i0 + prow];
    const int* adjRow = adj + (size_t)(i0 + prow) * NN;
    const short* hrow = h_t + ((size_t)t << 13);     // row t of h_t

    float16v acc00 = {}, acc01 = {}, acc10 = {}, acc11 = {};
    float lp = 0.f;

    // prologue: stage Fd[0], prefetch first adj
    if (t < 16) *(float4*)&Fd[0][t * 4] = *(const float4*)(f_dst + jbase + t * 4);
    int4 av0 = *(const int4*)(adjRow + jbase + pjq * 16);
    int4 av1 = *(const int4*)(adjRow + jbase + pjq * 16 + 4);
    int4 av2 = *(const int4*)(adjRow + jbase + pjq * 16 + 8);
    int4 av3 = *(const int4*)(adjRow + jbase + pjq * 16 + 12);
    __syncthreads();

    int buf = 0;
    for (int jo = 0; jo < jlen; jo += JTILE) {
        const int j0 = jbase + jo;
        // ---- phase 1: P compute + H stage ----
        {
            const float* fdc = &Fd[buf][pjq * 16];
            short8 pbl, pbh;
            int4 avs[4] = {av0, av1, av2, av3};
#pragma unroll
            for (int g = 0; g < 4; g++) {
                const int* ai = (const int*)&avs[g];
#pragma unroll
                for (int q = 0; q < 4; q++) {
                    float y = fs + fdc[g * 4 + q];
                    y = fmaxf(y, 0.2f * y);          // leaky_relu (valid in log2-scaled domain)
                    float e = exp2f(y);
                    float p = (ai[q] != 0) ? e : 0.f;
                    lp += p;
                    short pb = f2bf(p);
                    if (g < 2) pbl[g * 4 + q] = pb; else pbh[(g - 2) * 4 + q] = pb;
                }
            }
            *(short8*)&Pt[prow * 72 + pjq * 16] = pbl;
            *(short8*)&Pt[prow * 72 + pjq * 16 + 8] = pbh;
        }
        // stage Ht: thread t = feature row t, 64 j's = 8 x short8
#pragma unroll
        for (int q = 0; q < 8; q++)
            *(short8*)&Ht[t * 72 + q * 8] = *(const short8*)(hrow + j0 + q * 8);

        // prefetch next tile's adj + Fd (overlaps MFMA phase)
        if (jo + JTILE < jlen) {
            if (t < 16) *(float4*)&Fd[buf ^ 1][t * 4] = *(const float4*)(f_dst + j0 + JTILE + t * 4);
            av0 = *(const int4*)(adjRow + j0 + JTILE + pjq * 16);
            av1 = *(const int4*)(adjRow + j0 + JTILE + pjq * 16 + 4);
            av2 = *(const int4*)(adjRow + j0 + JTILE + pjq * 16 + 8);
            av3 = *(const int4*)(adjRow + j0 + JTILE + pjq * 16 + 12);
        }
        __syncthreads();

        // ---- phase 2: MFMA, 4 k-steps of 16 ----
#pragma unroll
        for (int kk = 0; kk < 4; kk++) {
            short8 a0 = *(const short8*)&Pt[l31 * 72 + kk * 16 + lq * 8];
            short8 a1 = *(const short8*)&Pt[(32 + l31) * 72 + kk * 16 + lq * 8];
            short8 b0 = *(const short8*)&Ht[(wn0 + l31) * 72 + kk * 16 + lq * 8];
            short8 b1 = *(const short8*)&Ht[(wn0 + 32 + l31) * 72 + kk * 16 + lq * 8];
            acc00 = __builtin_amdgcn_mfma_f32_32x32x16_bf16(a0, b0, acc00, 0, 0, 0);
            acc01 = __builtin_amdgcn_mfma_f32_32x32x16_bf16(a0, b1, acc01, 0, 0, 0);
            acc10 = __builtin_amdgcn_mfma_f32_32x32x16_bf16(a1, b0, acc10, 0, 0, 0);
            acc11 = __builtin_amdgcn_mfma_f32_32x32x16_bf16(a1, b1, acc11, 0, 0, 0);
        }
        buf ^= 1;
        __syncthreads();
    }

    // ---- epilogue: partial row-sum l, partial O ----
    lp += __shfl_xor(lp, 1);
    lp += __shfl_xor(lp, 2);
    if (pjq == 0) lpart[slice * NN + i0 + prow] = lp;

    float* obase = Opart + ((size_t)slice * NN + i0) * FOUT;
    // C/D 32x32: col = l31, row = (reg&3) + 8*(reg>>2) + 4*lq
#pragma unroll
    for (int rt = 0; rt < 2; rt++) {
#pragma unroll
        for (int nt = 0; nt < 2; nt++) {
            const float16v& av = rt == 0 ? (nt == 0 ? acc00 : acc01) : (nt == 0 ? acc10 : acc11);
#pragma unroll
            for (int reg = 0; reg < 16; reg++) {
                int row = rt * 32 + (reg & 3) + 8 * (reg >> 2) + 4 * lq;
                int n = wn0 + nt * 32 + l31;
                obase[(size_t)row * FOUT + n] = av[reg];
            }
        }
    }
}

// ---------------- Kernel 3: combine partials: out = sum_s O_s / sum_s l_s ----------------
__global__ __launch_bounds__(256) void combine_kernel(const float* __restrict__ Opart,
                                                      const float* __restrict__ lpart,
                                                      float* __restrict__ out, int slices) {
    int i = blockIdx.x, n = threadIdx.x;
    float o = 0.f, l = 0.f;
    for (int s = 0; s < slices; s++) {
        o += Opart[((size_t)s * NN + i) * FOUT + n];
        l += lpart[s * NN + i];
    }
    out[(size_t)i * FOUT + n] = o / l;
}

extern "C" void kernel_launch(void* const* d_in, const int* in_sizes, int n_in,
                              void* d_out, int out_size, void* d_ws, size_t ws_size,
                              hipStream_t stream) {
    const float* x   = (const float*)d_in[0];
    const int*   adj = (const int*)d_in[1];
    const float* W   = (const float*)d_in[2];
    const float* a   = (const float*)d_in[3];
    float* out = (float*)d_out;

    char* ws = (char*)d_ws;
    short* h_t   = (short*)ws;                                   // 4 MB
    short* Wt    = (short*)(ws + (4u << 20));                    // 256 KB
    float* f_src = (float*)(ws + (4u << 20) + (256u << 10));     // 32 KB
    float* f_dst = (float*)(ws + (4u << 20) + (288u << 10));     // 32 KB
    float* lpart = (float*)(ws + (4u << 20) + (320u << 10));     // 128 KB
    float* Opart = (float*)(ws + (5u << 20));                    // up to 32 MB

    const size_t OSLICE = (size_t)NN * FOUT * 4;                 // 8 MB per slice
    int slices = 1;
    if (ws_size >= (5u << 20) + 4 * OSLICE) slices = 4;
    else if (ws_size >= (5u << 20) + 2 * OSLICE) slices = 2;
    int jlen = NN / slices;

    hipMemsetAsync(f_src, 0, 2 * NN * sizeof(float), stream);
    wt_kernel<<<dim3(FIN / 32, FOUT / 32), 256, 0, stream>>>(W, Wt);
    h_kernel<<<512, 256, 0, stream>>>(x, Wt, a, h_t, f_src, f_dst);
    gat_kernel<<<dim3(NN / 64, slices), 256, 0, stream>>>(adj, h_t, f_src, f_dst,
                                                          Opart, lpart, jlen);
    combine_kernel<<<NN, 256, 0, stream>>>(Opart, lpart, out, slices);
}